// Round 2
// baseline (732.748 us; speedup 1.0000x reference)
//
#include <hip/hip_runtime.h>

typedef _Float16 f16;
typedef f16 f16x8 __attribute__((ext_vector_type(8)));
typedef f16 f16x4 __attribute__((ext_vector_type(4)));
typedef float f32x4 __attribute__((ext_vector_type(4)));

#define SCALE 0.17677669529663689f   // 1/sqrt(32)

// ws layout (bytes):
//   0      : wqp   packed Wq*scale  f16 [8 ot][4 kk][64 lane][8]   (32768)
//   32768  : wkvp  packed Wkv       f16 [16][4][64][8]             (65536)
//   98304  : wop   packed Wo        f16 [8][4][64][8]              (32768)
//   131072 : bqs   bq*scale f32[128]                               (512)
//   131584 : rbT   f32 [4 h][64 j][64 i]                           (65536)
//   200704 : emT   f16 [4096 w][64 j][64 i] = exp(mask[w][i][j])   (33554432)  [fast path only]
// fast-path total 33755136 bytes (~32.2 MB); base prep = 197120 bytes

#define WS_NEEDED_FAST 33755136ull

__global__ __launch_bounds__(256) void prep_kernel(
    const float* __restrict__ Wq, const float* __restrict__ bq,
    const float* __restrict__ Wkv, const float* __restrict__ Wo,
    const float* __restrict__ bias_table, char* __restrict__ ws) {
  int tid = blockIdx.x * 256 + threadIdx.x;
  f16* wqp = (f16*)ws;
  f16* wkvp = (f16*)(ws + 32768);
  f16* wop = (f16*)(ws + 98304);
  float* bqs = (float*)(ws + 131072);
  float* rbT = (float*)(ws + 131584);
  if (tid < 16384) {
    int t = tid & 7, l = (tid >> 3) & 63, kk = (tid >> 9) & 3, ot = tid >> 11;
    int o = (ot << 4) | (l & 15);
    int c = kk * 32 + ((l >> 4) << 3) + t;
    wqp[tid] = (f16)(Wq[o * 128 + c] * SCALE);
    wop[tid] = (f16)(Wo[o * 128 + c]);
  } else if (tid < 49152) {
    int p = tid - 16384;
    int t = p & 7, l = (p >> 3) & 63, kk = (p >> 9) & 3, ot = p >> 11;
    int o = (ot << 4) | (l & 15);           // 0..255
    int c = kk * 32 + ((l >> 4) << 3) + t;
    wkvp[p] = (f16)(Wkv[o * 128 + c]);
  } else if (tid < 65536) {
    int p = tid - 49152;                    // rbT index: [h][j][i]
    int h = p >> 12, j = (p >> 6) & 63, i = p & 63;
    int rpi = ((i >> 3) - (j >> 3) + 7) * 15 + ((i & 7) - (j & 7) + 7);
    rbT[p] = bias_table[rpi * 4 + h];
  } else if (tid < 65664) {
    int o = tid - 65536;
    bqs[o] = bq[o] * SCALE;
  }
}

// emT[w][j][i] = exp(mask[w][i][j]), fp16, one block per window
__global__ __launch_bounds__(256) void emT_kernel(const float* __restrict__ mask,
                                                  f16* __restrict__ emT) {
  __shared__ float lds[64 * 65];
  int w = blockIdx.x, t = threadIdx.x;
  const float4* mp = (const float4*)(mask + (size_t)w * 4096);
#pragma unroll
  for (int it = 0; it < 4; it++) {
    int fi = it * 256 + t;                  // float4 index 0..1023
    float4 v = mp[fi];
    int flat = fi * 4;
    int i = flat >> 6, j = flat & 63;
    lds[i * 65 + j + 0] = v.x;
    lds[i * 65 + j + 1] = v.y;
    lds[i * 65 + j + 2] = v.z;
    lds[i * 65 + j + 3] = v.w;
  }
  __syncthreads();
  // each thread produces 16 consecutive outputs: of = t*16+k -> j=t>>2, i=(t&3)*16+k
  int j = t >> 2;
  f16x8 o0, o1;
#pragma unroll
  for (int k = 0; k < 8; k++) {
    int i = (t & 3) * 16 + k;
    o0[k] = (f16)__expf(lds[i * 65 + j]);
  }
#pragma unroll
  for (int k = 8; k < 16; k++) {
    int i = (t & 3) * 16 + k;
    o1[k - 8] = (f16)__expf(lds[i * 65 + j]);
  }
  f16* dst = emT + (size_t)w * 4096 + t * 16;
  *(f16x8*)dst = o0;
  *(f16x8*)(dst + 8) = o1;
}

// LDS map (bytes), region-aliased across phases:
//   [0,16384)      q-stage f16 [64][128] swz   ->  qh f16 [64][128] swz  -> x f16 [64][128] swz
//   [16384,32768)  kv-stage f16 [64][128] swz  ->  k  f16 [64][128] swz
//   [32768,49152)  vT f16 [128][64] swz
//   [49152,69632)  P per-wave [64][40] f16 (5120 B each)
#define LDS_BYTES 69632

template <bool USE_EMT>
__global__ __launch_bounds__(256, 2) void win_attn(
    const float* __restrict__ qin, const float* __restrict__ kvin,
    const float* __restrict__ bkv, const float* __restrict__ bo,
    const char* __restrict__ ws, const float* __restrict__ mask,
    float* __restrict__ out) {
  __shared__ char smem[LDS_BYTES];
  const int tid = threadIdx.x;
  const int w = tid >> 6;      // wave id == head id
  const int l = tid & 63;
  const int g = l >> 4;
  const int cl = l & 15;
  const int b = blockIdx.x;
  const int wm = b & 4095;     // mask window index

  const f16* wqp = (const f16*)ws;
  const f16* wkvp = (const f16*)(ws + 32768);
  const f16* wop = (const f16*)(ws + 98304);
  const float* bqs = (const float*)(ws + 131072);
  const float* rbT = (const float*)(ws + 131584);
  const f16* emT = (const f16*)(ws + 200704);

  // ---- Phase 1: stage q, kv to LDS as f16 (row-XOR swizzled) ----
  {
    const float4* qp = (const float4*)(qin + (size_t)b * 8192);
    const float4* kp = (const float4*)(kvin + (size_t)b * 8192);
#pragma unroll
    for (int it = 0; it < 8; it++) {
      int fi = it * 256 + tid;            // float4 idx; 32 per row
      int row = fi >> 5;
      int c0 = (fi & 31) << 2;            // col (elements)
      int off = (row * 256 + c0 * 2) ^ ((row & 7) << 4);
      float4 v = qp[fi];
      f16x4 h = {(f16)v.x, (f16)v.y, (f16)v.z, (f16)v.w};
      *(f16x4*)(smem + off) = h;
      float4 u = kp[fi];
      f16x4 h2 = {(f16)u.x, (f16)u.y, (f16)u.z, (f16)u.w};
      *(f16x4*)(smem + 16384 + off) = h2;
    }
  }
  __syncthreads();

  // ---- Phase 2: q projection; wave w -> qh cols [32w, 32w+32) ----
  f32x4 qacc[4][2] = {};
#pragma unroll
  for (int kk = 0; kk < 4; kk++) {
    f16x8 bf[2];
#pragma unroll
    for (int nt = 0; nt < 2; nt++) {
      int ot = 2 * w + nt;
      bf[nt] = *(const f16x8*)(wqp + ((ot * 4 + kk) * 64 + l) * 8);
    }
#pragma unroll
    for (int m = 0; m < 4; m++) {
      int row = 16 * m + cl;
      int off = (row * 256 + (kk * 32 + g * 8) * 2) ^ ((cl & 7) << 4);
      f16x8 a = *(const f16x8*)(smem + off);
#pragma unroll
      for (int nt = 0; nt < 2; nt++)
        qacc[m][nt] = __builtin_amdgcn_mfma_f32_16x16x32_f16(a, bf[nt], qacc[m][nt], 0, 0, 0);
    }
  }
  float bqv0 = bqs[32 * w + cl], bqv1 = bqs[32 * w + 16 + cl];
  __syncthreads();  // all waves done reading q-stage; [0,16K) becomes qh
#pragma unroll
  for (int m = 0; m < 4; m++)
#pragma unroll
    for (int nt = 0; nt < 2; nt++) {
      float bb = nt ? bqv1 : bqv0;
#pragma unroll
      for (int r = 0; r < 4; r++) {
        int n = 16 * m + 4 * g + r;
        int d = 32 * w + 16 * nt + cl;
        int off = (n * 256 + d * 2) ^ ((n & 7) << 4);
        *(f16*)(smem + off) = (f16)(qacc[m][nt][r] + bb);
      }
    }

  // ---- Phase 3: kv projection; wave w -> kvh cols [64w, 64w+64) ----
  f32x4 kvacc[4][4] = {};
#pragma unroll
  for (int kk = 0; kk < 4; kk++) {
    f16x8 bf[4];
#pragma unroll
    for (int nt = 0; nt < 4; nt++) {
      int ot = 4 * w + nt;
      bf[nt] = *(const f16x8*)(wkvp + ((ot * 4 + kk) * 64 + l) * 8);
    }
#pragma unroll
    for (int m = 0; m < 4; m++) {
      int row = 16 * m + cl;
      int off = 16384 + ((row * 256 + (kk * 32 + g * 8) * 2) ^ ((cl & 7) << 4));
      f16x8 a = *(const f16x8*)(smem + off);
#pragma unroll
      for (int nt = 0; nt < 4; nt++)
        kvacc[m][nt] = __builtin_amdgcn_mfma_f32_16x16x32_f16(a, bf[nt], kvacc[m][nt], 0, 0, 0);
    }
  }
  float bkvv[4];
#pragma unroll
  for (int nt = 0; nt < 4; nt++) bkvv[nt] = bkv[64 * w + 16 * nt + cl];
  __syncthreads();  // all waves done reading kv-stage; [16K,32K) becomes k
  if (w < 2) {
    // k part: k_lds[j][d], d in [0,128)
#pragma unroll
    for (int m = 0; m < 4; m++)
#pragma unroll
      for (int nt = 0; nt < 4; nt++)
#pragma unroll
        for (int r = 0; r < 4; r++) {
          int j = 16 * m + 4 * g + r;
          int d = 64 * w + 16 * nt + cl;
          int off = 16384 + ((j * 256 + d * 2) ^ ((j & 7) << 4));
          *(f16*)(smem + off) = (f16)(kvacc[m][nt][r] + bkvv[nt]);
        }
  } else {
    // v part transposed: vT[d][j], d in [0,128)
#pragma unroll
    for (int m = 0; m < 4; m++)
#pragma unroll
      for (int nt = 0; nt < 4; nt++)
#pragma unroll
        for (int r = 0; r < 4; r++) {
          int j = 16 * m + 4 * g + r;
          int d = 64 * (w - 2) + 16 * nt + cl;
          int off = 32768 + ((d * 128 + j * 2) ^ ((d & 7) << 4));
          *(f16*)(smem + off) = (f16)(kvacc[m][nt][r] + bkvv[nt]);
        }
  }
  __syncthreads();

  // ---- Phase 4: QK^T (transposed: att[j][i]) + bias + exp, head = w ----
  f32x4 att[4][4] = {};  // [jt][it]
  {
    f16x8 bqh[4];
#pragma unroll
    for (int it = 0; it < 4; it++) {
      int i = 16 * it + cl;
      int off = (i * 256 + (32 * w + 8 * g) * 2) ^ ((cl & 7) << 4);
      bqh[it] = *(const f16x8*)(smem + off);
    }
#pragma unroll
    for (int jt = 0; jt < 4; jt++) {
      int j = 16 * jt + cl;
      int off = 16384 + ((j * 256 + (32 * w + 8 * g) * 2) ^ ((cl & 7) << 4));
      f16x8 ak = *(const f16x8*)(smem + off);
#pragma unroll
      for (int it = 0; it < 4; it++)
        att[jt][it] = __builtin_amdgcn_mfma_f32_16x16x32_f16(ak, bqh[it], att[jt][it], 0, 0, 0);
    }
  }
  {
    const float* rbp = rbT + w * 4096;
    const f16* emp = emT + (size_t)wm * 4096;
    const float* maskp = mask + (size_t)wm * 4096;
#pragma unroll
    for (int jt = 0; jt < 4; jt++)
#pragma unroll
      for (int it = 0; it < 4; it++)
#pragma unroll
        for (int r = 0; r < 4; r++) {
          int j = 16 * jt + 4 * g + r;
          int i = 16 * it + cl;
          float rb = rbp[j * 64 + i];
          if (USE_EMT) {
            float em = (float)emp[j * 64 + i];
            att[jt][it][r] = __expf(att[jt][it][r] + rb) * em;
          } else {
            float mv = maskp[i * 64 + j];   // mask[w][i][j], uncoalesced fallback
            att[jt][it][r] = __expf(att[jt][it][r] + rb + mv);
          }
        }
  }
  float rinv[4];
#pragma unroll
  for (int it = 0; it < 4; it++) {
    float s = 0.f;
#pragma unroll
    for (int jt = 0; jt < 4; jt++)
      s += (att[jt][it][0] + att[jt][it][1]) + (att[jt][it][2] + att[jt][it][3]);
    s += __shfl_xor(s, 16, 64);
    s += __shfl_xor(s, 32, 64);
    rinv[it] = 1.0f / s;
  }

  // ---- Phase 5: PV (xT[d][i]), j in two K=32 chunks through per-wave P buffer ----
  char* Pbase = smem + 49152 + w * 5120;   // [64 i][40 jj] f16
  f32x4 xt[2][4] = {};                     // [dt][it]
#pragma unroll
  for (int ch = 0; ch < 2; ch++) {
#pragma unroll
    for (int jh = 0; jh < 2; jh++) {
      int jt = 2 * ch + jh;
#pragma unroll
      for (int it = 0; it < 4; it++) {
        int i = 16 * it + cl;
        f16x4 pv = {(f16)att[jt][it][0], (f16)att[jt][it][1],
                    (f16)att[jt][it][2], (f16)att[jt][it][3]};
        int jj0 = 16 * jh + 4 * g;
        *(f16x4*)(Pbase + (i * 40 + jj0) * 2) = pv;
      }
    }
    f16x8 av[2];
#pragma unroll
    for (int dt = 0; dt < 2; dt++) {
      int dg = 32 * w + 16 * dt + cl;
      int off = 32768 + ((dg * 128 + (32 * ch + 8 * g) * 2) ^ ((dg & 7) << 4));
      av[dt] = *(const f16x8*)(smem + off);
    }
#pragma unroll
    for (int it = 0; it < 4; it++) {
      int i = 16 * it + cl;
      f16x8 bp = *(const f16x8*)(Pbase + (i * 40 + 8 * g) * 2);
#pragma unroll
      for (int dt = 0; dt < 2; dt++)
        xt[dt][it] = __builtin_amdgcn_mfma_f32_16x16x32_f16(av[dt], bp, xt[dt][it], 0, 0, 0);
    }
  }
#pragma unroll
  for (int dt = 0; dt < 2; dt++)
#pragma unroll
    for (int it = 0; it < 4; it++)
#pragma unroll
      for (int r = 0; r < 4; r++) xt[dt][it][r] *= rinv[it];
  __syncthreads();  // qh reads complete everywhere; [0,16K) becomes x
#pragma unroll
  for (int dt = 0; dt < 2; dt++)
#pragma unroll
    for (int it = 0; it < 4; it++)
#pragma unroll
      for (int r = 0; r < 4; r++) {
        int d = 16 * dt + 4 * g + r;      // local col in head
        int n = 16 * it + cl;             // row
        int off = (n * 256 + (32 * w + d) * 2) ^ ((n & 7) << 4);
        *(f16*)(smem + off) = (f16)xt[dt][it][r];
      }
  __syncthreads();

  // ---- Phase 6: output projection; wave w -> out cols [32w, 32w+32) ----
  f32x4 oacc[4][2] = {};
#pragma unroll
  for (int kk = 0; kk < 4; kk++) {
    f16x8 bf[2];
#pragma unroll
    for (int nt = 0; nt < 2; nt++) {
      int ot = 2 * w + nt;
      bf[nt] = *(const f16x8*)(wop + ((ot * 4 + kk) * 64 + l) * 8);
    }
#pragma unroll
    for (int m = 0; m < 4; m++) {
      int row = 16 * m + cl;
      int off = (row * 256 + (kk * 32 + g * 8) * 2) ^ ((cl & 7) << 4);
      f16x8 a = *(const f16x8*)(smem + off);
#pragma unroll
      for (int nt = 0; nt < 2; nt++)
        oacc[m][nt] = __builtin_amdgcn_mfma_f32_16x16x32_f16(a, bf[nt], oacc[m][nt], 0, 0, 0);
    }
  }
  float bov0 = bo[32 * w + cl], bov1 = bo[32 * w + 16 + cl];
  float* op = out + (size_t)b * 8192;
#pragma unroll
  for (int m = 0; m < 4; m++)
#pragma unroll
    for (int nt = 0; nt < 2; nt++) {
      float bb = nt ? bov1 : bov0;
#pragma unroll
      for (int r = 0; r < 4; r++) {
        int n = 16 * m + 4 * g + r;
        int o = 32 * w + 16 * nt + cl;
        op[n * 128 + o] = oacc[m][nt][r] + bb;
      }
    }
}

extern "C" void kernel_launch(void* const* d_in, const int* in_sizes, int n_in,
                              void* d_out, int out_size, void* d_ws, size_t ws_size,
                              hipStream_t stream) {
  const float* q    = (const float*)d_in[0];
  const float* kv   = (const float*)d_in[1];
  const float* mask = (const float*)d_in[2];
  const float* Wq   = (const float*)d_in[3];
  const float* bq   = (const float*)d_in[4];
  const float* Wkv  = (const float*)d_in[5];
  const float* bkv  = (const float*)d_in[6];
  const float* Wo   = (const float*)d_in[7];
  const float* bo   = (const float*)d_in[8];
  const float* bt   = (const float*)d_in[9];
  char* ws = (char*)d_ws;

  prep_kernel<<<257, 256, 0, stream>>>(Wq, bq, Wkv, Wo, bt, ws);
  if (ws_size >= WS_NEEDED_FAST) {
    emT_kernel<<<4096, 256, 0, stream>>>(mask, (f16*)(ws + 200704));
    win_attn<true><<<8192, 256, 0, stream>>>(q, kv, bkv, bo, ws, mask, (float*)d_out);
  } else {
    win_attn<false><<<8192, 256, 0, stream>>>(q, kv, bkv, bo, ws, mask, (float*)d_out);
  }
}